// Round 1
// baseline (972.640 us; speedup 1.0000x reference)
//
#include <hip/hip_runtime.h>

#define N_TOK 8192
#define DIM   2048
#define FFN   1408
#define NEXP  8

// ---------- ws layout (bytes) ----------
#define X_OFF   0ull                          // x bf16 [N][D]            33,554,432
#define WG_OFF  33554432ull                   // wg_t bf16 [E][F][D]      46,137,344
#define WU_OFF  79691776ull
#define WD_OFF  125829120ull                  // wd_t bf16 [E][D][F]
#define H_OFF   171966464ull                  // h bf16 [2N][F]           46,137,344
#define LPK_OFF 218103808ull                  // list packed tok<<1|k [2N] int
#define LW_OFF  218169344ull                  // list weight [2N] f32
#define TI_OFF  218234880ull                  // per-token top idx packed [N] int
#define TW_OFF  218267648ull                  // per-token w1 [N] f32
#define ST_OFF  218300416ull                  // cnt[8] cursor[8] base[8] pad psum_u64[8]

typedef __bf16 bf16x8 __attribute__((ext_vector_type(8)));
typedef float  f32x4  __attribute__((ext_vector_type(4)));
typedef __attribute__((address_space(1))) void as1_void;
typedef __attribute__((address_space(3))) void as3_void;

__device__ __forceinline__ void gload16(const void* g, void* l) {
  __builtin_amdgcn_global_load_lds((as1_void*)g, (as3_void*)l, 16, 0, 0);
}

__device__ __forceinline__ ushort f2bf(float f) {
  unsigned u = __builtin_bit_cast(unsigned, f);
  u += 0x7FFFu + ((u >> 16) & 1u);
  return (ushort)(u >> 16);
}

// ---------------- router: logits, softmax, top2, x->bf16, stats ----------------
__global__ __launch_bounds__(256) void router_kernel(
    const float* __restrict__ x, const float* __restrict__ rw,
    ushort* __restrict__ xb, int* __restrict__ topi, float* __restrict__ topw,
    int* __restrict__ cnt, unsigned long long* __restrict__ psum)
{
  int tid = threadIdx.x, lane = tid & 63, wv = tid >> 6;
  __shared__ float sP[4][8];
  __shared__ int   sC[4][8];
  float pacc[8]; int cacc[8];
  #pragma unroll
  for (int e = 0; e < 8; ++e) { pacc[e] = 0.f; cacc[e] = 0; }

  #pragma unroll 1
  for (int it = 0; it < 4; ++it) {
    int t = blockIdx.x * 16 + wv * 4 + it;
    const float4* xr = (const float4*)(x + (size_t)t * DIM);
    float acc[8];
    #pragma unroll
    for (int e = 0; e < 8; ++e) acc[e] = 0.f;
    #pragma unroll 1
    for (int i = 0; i < 8; ++i) {
      int j = i * 64 + lane;
      float4 v = xr[j];
      ushort4 o; o.x = f2bf(v.x); o.y = f2bf(v.y); o.z = f2bf(v.z); o.w = f2bf(v.w);
      *(ushort4*)(xb + (size_t)t * DIM + (size_t)j * 4) = o;
      const float* rr = rw + (size_t)j * 32;  // rows 4j..4j+3, 8 cols each
      #pragma unroll
      for (int c = 0; c < 4; ++c) {
        float xv = (&v.x)[c];
        const float4* r4 = (const float4*)(rr + c * 8);
        float4 q0 = r4[0], q1 = r4[1];
        acc[0] += xv * q0.x; acc[1] += xv * q0.y; acc[2] += xv * q0.z; acc[3] += xv * q0.w;
        acc[4] += xv * q1.x; acc[5] += xv * q1.y; acc[6] += xv * q1.z; acc[7] += xv * q1.w;
      }
    }
    #pragma unroll
    for (int off = 32; off; off >>= 1) {
      #pragma unroll
      for (int e = 0; e < 8; ++e) acc[e] += __shfl_xor(acc[e], off);
    }
    float m = acc[0];
    #pragma unroll
    for (int e = 1; e < 8; ++e) m = fmaxf(m, acc[e]);
    float p[8], s = 0.f;
    #pragma unroll
    for (int e = 0; e < 8; ++e) { p[e] = __expf(acc[e] - m); s += p[e]; }
    float inv = 1.f / s;
    int i1 = 0; float p1 = p[0];
    #pragma unroll
    for (int e = 1; e < 8; ++e) if (p[e] > p1) { p1 = p[e]; i1 = e; }
    int i2 = -1; float p2 = -1.f;
    #pragma unroll
    for (int e = 0; e < 8; ++e) if (e != i1 && p[e] > p2) { p2 = p[e]; i2 = e; }
    float w1 = p1 / (p1 + p2);
    if (lane == 0) {
      topi[t] = i1 | (i2 << 8);
      topw[t] = w1;
      #pragma unroll
      for (int e = 0; e < 8; ++e) pacc[e] += p[e] * inv;
      cacc[i1]++; cacc[i2]++;
    }
  }
  if (lane == 0) {
    #pragma unroll
    for (int e = 0; e < 8; ++e) { sP[wv][e] = pacc[e]; sC[wv][e] = cacc[e]; }
  }
  __syncthreads();
  if (tid < 8) {
    float ps = sP[0][tid] + sP[1][tid] + sP[2][tid] + sP[3][tid];
    int   cs = sC[0][tid] + sC[1][tid] + sC[2][tid] + sC[3][tid];
    atomicAdd(&cnt[tid], cs);
    atomicAdd(&psum[tid], (unsigned long long)((double)ps * 1099511627776.0));
  }
}

// ---------------- scan + aux ----------------
__global__ void scan_aux_kernel(int* __restrict__ stats,
                                const unsigned long long* __restrict__ psum,
                                float* __restrict__ aux_out)
{
  if (threadIdx.x == 0 && blockIdx.x == 0) {
    int b = 0;
    for (int e = 0; e < 8; ++e) { stats[16 + e] = b; stats[8 + e] = b; b += stats[e]; }
    double s = 0.0;
    for (int e = 0; e < 8; ++e)
      s += (double)stats[e] * ((double)psum[e] * (1.0 / 1099511627776.0));
    aux_out[0] = (float)(4.0 * s / ((double)N_TOK * (double)N_TOK));
  }
}

// ---------------- placement ----------------
__global__ __launch_bounds__(256) void place_kernel(
    const int* __restrict__ topi, const float* __restrict__ topw,
    int* __restrict__ stats, int* __restrict__ lpk, float* __restrict__ lw)
{
  int t = blockIdx.x * 256 + threadIdx.x;
  if (t >= N_TOK) return;
  int pk = topi[t];
  int e1 = pk & 0xff, e2 = (pk >> 8) & 0xff;
  float w1 = topw[t];
  int p1 = atomicAdd(&stats[8 + e1], 1);
  lpk[p1] = (t << 1); lw[p1] = w1;
  int p2 = atomicAdd(&stats[8 + e2], 1);
  lpk[p2] = (t << 1) | 1; lw[p2] = 1.f - w1;
}

// ---------------- transpose-convert f32 -> bf16 ----------------
// src [E][R][C] f32  ->  dst [E][C][R] bf16
__global__ __launch_bounds__(256) void conv_t_kernel(
    const float* __restrict__ src, ushort* __restrict__ dst, int R, int C)
{
  __shared__ float t[32][33];
  int e = blockIdx.z;
  int rb = blockIdx.y << 5, cb = blockIdx.x << 5;
  int x = threadIdx.x & 31, y = threadIdx.x >> 5;
  const float* s = src + ((size_t)e * R + rb) * C + cb;
  #pragma unroll
  for (int i = 0; i < 4; ++i) t[y + i * 8][x] = s[(size_t)(y + i * 8) * C + x];
  __syncthreads();
  ushort* d = dst + ((size_t)e * C + cb) * R + rb;
  #pragma unroll
  for (int i = 0; i < 4; ++i) { int c = y + i * 8; d[(size_t)c * R + x] = f2bf(t[x][c]); }
}

#define MFMA16(a, b, c) __builtin_amdgcn_mfma_f32_16x16x32_bf16(a, b, c, 0, 0, 0)

// ---------------- GEMM1: h = silu(x@Wg) * (x@Wu), gathered rows ----------------
__global__ __launch_bounds__(256, 2) void gemm_gateup_kernel(
    const ushort* __restrict__ xb, const ushort* __restrict__ wgt,
    const ushort* __restrict__ wut, const int* __restrict__ lpk,
    const int* __restrict__ stats, ushort* __restrict__ h)
{
  int e = blockIdx.z;
  int Me = stats[e];
  int tm = blockIdx.x;
  if (tm * 128 >= Me) return;
  int abase = stats[16 + e];
  int tn = blockIdx.y;

  __shared__ ushort As[128 * 32];
  __shared__ ushort Bg[128 * 32];
  __shared__ ushort Bu[128 * 32];
  __shared__ int rofs[128];

  int tid = threadIdx.x;
  if (tid < 128) {
    int gr = tm * 128 + tid;
    int pk = lpk[abase + ((gr < Me) ? gr : 0)];
    rofs[tid] = (pk >> 1) * DIM;
  }
  __syncthreads();

  int lane = tid & 63, wv = tid >> 6;
  int wm = wv >> 1, wn = wv & 1;
  int srow = wv * 16 + (lane >> 2);
  int scol = (lane & 3) * 8;
  int ro0 = rofs[srow], ro1 = rofs[srow + 64];
  const ushort* a0 = xb + ro0 + scol;
  const ushort* a1 = xb + ro1 + scol;
  const ushort* g0 = wgt + ((size_t)e * FFN + tn * 128 + srow) * DIM + scol;
  const ushort* g1 = g0 + (size_t)64 * DIM;
  const ushort* u0 = wut + ((size_t)e * FFN + tn * 128 + srow) * DIM + scol;
  const ushort* u1 = u0 + (size_t)64 * DIM;

  char* AsB = (char*)As + wv * 1024;
  char* BgB = (char*)Bg + wv * 1024;
  char* BuB = (char*)Bu + wv * 1024;

  const ushort* ap = As + (wm * 64 + (lane & 15)) * 32 + (lane >> 4) * 8;
  const ushort* gp = Bg + (wn * 64 + (lane & 15)) * 32 + (lane >> 4) * 8;
  const ushort* up = Bu + (wn * 64 + (lane & 15)) * 32 + (lane >> 4) * 8;

  f32x4 accg[4][4], accu[4][4];
  #pragma unroll
  for (int m = 0; m < 4; ++m)
    #pragma unroll
    for (int n = 0; n < 4; ++n) { accg[m][n] = (f32x4){0,0,0,0}; accu[m][n] = (f32x4){0,0,0,0}; }

  #pragma unroll 1
  for (int k0 = 0; k0 < DIM; k0 += 32) {
    gload16(a0 + k0, AsB);        gload16(a1 + k0, AsB + 4096);
    gload16(g0 + k0, BgB);        gload16(g1 + k0, BgB + 4096);
    gload16(u0 + k0, BuB);        gload16(u1 + k0, BuB + 4096);
    __syncthreads();
    bf16x8 av[4], gv[4], uv[4];
    #pragma unroll
    for (int m = 0; m < 4; ++m) av[m] = *(const bf16x8*)(ap + m * 512);
    #pragma unroll
    for (int n = 0; n < 4; ++n) gv[n] = *(const bf16x8*)(gp + n * 512);
    #pragma unroll
    for (int n = 0; n < 4; ++n) uv[n] = *(const bf16x8*)(up + n * 512);
    #pragma unroll
    for (int m = 0; m < 4; ++m)
      #pragma unroll
      for (int n = 0; n < 4; ++n) {
        accg[m][n] = MFMA16(av[m], gv[n], accg[m][n]);
        accu[m][n] = MFMA16(av[m], uv[n], accu[m][n]);
      }
    __syncthreads();
  }

  int r0 = lane >> 4, c = lane & 15;
  #pragma unroll
  for (int m = 0; m < 4; ++m)
    #pragma unroll
    for (int n = 0; n < 4; ++n)
      #pragma unroll
      for (int r = 0; r < 4; ++r) {
        int row = wm * 64 + m * 16 + r0 * 4 + r;
        if (tm * 128 + row < Me) {
          float g = accg[m][n][r], u = accu[m][n][r];
          float hv = g * u / (1.f + __expf(-g));
          h[(size_t)(abase + tm * 128 + row) * FFN + tn * 128 + wn * 64 + n * 16 + c] = f2bf(hv);
        }
      }
}

// ---------------- GEMM2: out += w * (h @ Wd), scatter by token ----------------
__global__ __launch_bounds__(256, 2) void gemm_down_kernel(
    const ushort* __restrict__ h, const ushort* __restrict__ wdt,
    const int* __restrict__ lpk, const float* __restrict__ lw,
    const int* __restrict__ stats, float* __restrict__ out)
{
  int e = blockIdx.z;
  int Me = stats[e];
  int tm = blockIdx.x;
  if (tm * 128 >= Me) return;
  int abase = stats[16 + e];
  int tn = blockIdx.y;

  __shared__ ushort As[128 * 32];
  __shared__ ushort Bs[128 * 32];
  __shared__ int   pkl[128];
  __shared__ float wl[128];

  int tid = threadIdx.x;
  if (tid < 128) {
    int gr = tm * 128 + tid;
    pkl[tid] = (gr < Me) ? lpk[abase + gr] : 0;
    wl[tid]  = (gr < Me) ? lw[abase + gr] : 0.f;
  }

  int lane = tid & 63, wv = tid >> 6;
  int wm = wv >> 1, wn = wv & 1;
  int srow = wv * 16 + (lane >> 2);
  int scol = (lane & 3) * 8;
  const ushort* a0 = h + ((size_t)(abase + tm * 128 + srow)) * FFN + scol;
  const ushort* a1 = a0 + (size_t)64 * FFN;
  const ushort* b0 = wdt + ((size_t)e * DIM + tn * 128 + srow) * FFN + scol;
  const ushort* b1 = b0 + (size_t)64 * FFN;
  char* AsB = (char*)As + wv * 1024;
  char* BsB = (char*)Bs + wv * 1024;
  const ushort* ap = As + (wm * 64 + (lane & 15)) * 32 + (lane >> 4) * 8;
  const ushort* bp = Bs + (wn * 64 + (lane & 15)) * 32 + (lane >> 4) * 8;

  f32x4 acc[4][4];
  #pragma unroll
  for (int m = 0; m < 4; ++m)
    #pragma unroll
    for (int n = 0; n < 4; ++n) acc[m][n] = (f32x4){0,0,0,0};

  #pragma unroll 1
  for (int k0 = 0; k0 < FFN; k0 += 32) {
    gload16(a0 + k0, AsB);  gload16(a1 + k0, AsB + 4096);
    gload16(b0 + k0, BsB);  gload16(b1 + k0, BsB + 4096);
    __syncthreads();
    bf16x8 av[4], bv[4];
    #pragma unroll
    for (int m = 0; m < 4; ++m) av[m] = *(const bf16x8*)(ap + m * 512);
    #pragma unroll
    for (int n = 0; n < 4; ++n) bv[n] = *(const bf16x8*)(bp + n * 512);
    #pragma unroll
    for (int m = 0; m < 4; ++m)
      #pragma unroll
      for (int n = 0; n < 4; ++n)
        acc[m][n] = MFMA16(av[m], bv[n], acc[m][n]);
    __syncthreads();
  }

  int r0 = lane >> 4, c = lane & 15;
  #pragma unroll
  for (int m = 0; m < 4; ++m)
    #pragma unroll
    for (int n = 0; n < 4; ++n)
      #pragma unroll
      for (int r = 0; r < 4; ++r) {
        int row = wm * 64 + m * 16 + r0 * 4 + r;
        if (tm * 128 + row < Me) {
          int t = pkl[row] >> 1;
          float val = wl[row] * acc[m][n][r];
          unsafeAtomicAdd(&out[(size_t)t * DIM + tn * 128 + wn * 64 + n * 16 + c], val);
        }
      }
}

extern "C" void kernel_launch(void* const* d_in, const int* in_sizes, int n_in,
                              void* d_out, int out_size, void* d_ws, size_t ws_size,
                              hipStream_t stream)
{
  const float* x  = (const float*)d_in[0];
  const float* rw = (const float*)d_in[1];
  const float* wg = (const float*)d_in[2];
  const float* wu = (const float*)d_in[3];
  const float* wd = (const float*)d_in[4];
  float* out = (float*)d_out;

  char* ws = (char*)d_ws;
  ushort* xb   = (ushort*)(ws + X_OFF);
  ushort* wgt  = (ushort*)(ws + WG_OFF);
  ushort* wut  = (ushort*)(ws + WU_OFF);
  ushort* wdt  = (ushort*)(ws + WD_OFF);
  ushort* hbuf = (ushort*)(ws + H_OFF);
  int*    lpk  = (int*)(ws + LPK_OFF);
  float*  lw   = (float*)(ws + LW_OFF);
  int*    topi = (int*)(ws + TI_OFF);
  float*  topw = (float*)(ws + TW_OFF);
  int*    stats = (int*)(ws + ST_OFF);
  unsigned long long* psum = (unsigned long long*)(ws + ST_OFF + 96);

  hipMemsetAsync(d_out, 0, (size_t)out_size * sizeof(float), stream);
  hipMemsetAsync(ws + ST_OFF, 0, 160, stream);

  router_kernel<<<512, 256, 0, stream>>>(x, rw, xb, topi, topw, stats, psum);
  scan_aux_kernel<<<1, 64, 0, stream>>>(stats, psum, out + (size_t)out_size - 1);
  place_kernel<<<32, 256, 0, stream>>>(topi, topw, stats, lpk, lw);

  conv_t_kernel<<<dim3(44, 64, 8), 256, 0, stream>>>(wg, wgt, DIM, FFN);
  conv_t_kernel<<<dim3(44, 64, 8), 256, 0, stream>>>(wu, wut, DIM, FFN);
  conv_t_kernel<<<dim3(64, 44, 8), 256, 0, stream>>>(wd, wdt, FFN, DIM);

  gemm_gateup_kernel<<<dim3(64, 11, 8), 256, 0, stream>>>(xb, wgt, wut, lpk, stats, hbuf);
  gemm_down_kernel<<<dim3(64, 16, 8), 256, 0, stream>>>(hbuf, wdt, lpk, lw, stats, out);
}

// Round 2
// 929.453 us; speedup vs baseline: 1.0465x; 1.0465x over previous
//
#include <hip/hip_runtime.h>

#define N_TOK 8192
#define DIM   2048
#define FFN   1408
#define NEXP  8

// ---------- ws layout (bytes) ----------
#define X_OFF   0ull                          // x bf16 [N][D]
#define WG_OFF  33554432ull                   // wg_t bf16 [E][F][D]
#define WU_OFF  79691776ull
#define WD_OFF  125829120ull                  // wd_t bf16 [E][D][F]
#define H_OFF   171966464ull                  // h bf16 [2N][F]
#define LPK_OFF 218103808ull
#define LW_OFF  218169344ull
#define TI_OFF  218234880ull
#define TW_OFF  218267648ull
#define ST_OFF  218300416ull

typedef __bf16 bf16x8 __attribute__((ext_vector_type(8)));
typedef float  f32x4  __attribute__((ext_vector_type(4)));
typedef int    int4v  __attribute__((ext_vector_type(4)));
typedef __attribute__((address_space(1))) void as1_void;
typedef __attribute__((address_space(3))) void as3_void;

__device__ __forceinline__ void gload16(const void* g, void* l) {
  __builtin_amdgcn_global_load_lds((as1_void*)g, (as3_void*)l, 16, 0, 0);
}

__device__ __forceinline__ ushort f2bf(float f) {
  unsigned u = __builtin_bit_cast(unsigned, f);
  u += 0x7FFFu + ((u >> 16) & 1u);
  return (ushort)(u >> 16);
}

__device__ __forceinline__ int4v dsread(int addr) {
  int4v d;
  asm volatile("ds_read_b128 %0, %1" : "=v"(d) : "v"(addr));
  return d;
}

#define WAITL() do { asm volatile("s_waitcnt lgkmcnt(0)" ::: "memory"); \
                     __builtin_amdgcn_sched_barrier(0); } while (0)
#define BAR()   __builtin_amdgcn_s_barrier()
#define MFMA16(a, b, c) __builtin_amdgcn_mfma_f32_16x16x32_bf16(a, b, c, 0, 0, 0)
#define BC(x) __builtin_bit_cast(bf16x8, x)

// swizzled byte offset within a [rows][32] bf16 unit (row-pair XOR involution)
__device__ __forceinline__ int swz(int row, int s) {
  int p = ((row & 1) << 2) | s;
  return ((row >> 1) << 7) + ((p ^ ((row >> 1) & 7)) << 4);
}
// inverse map: linear 16B-block L -> (row, slot) whose data must live there
__device__ __forceinline__ void decode(int L, int& row, int& slot) {
  int R = L >> 3, q = (L & 7) ^ (R & 7);
  row = (R << 1) | (q >> 2); slot = q & 3;
}

// ---------------- router ----------------
__global__ __launch_bounds__(256) void router_kernel(
    const float* __restrict__ x, const float* __restrict__ rw,
    ushort* __restrict__ xb, int* __restrict__ topi, float* __restrict__ topw,
    int* __restrict__ cnt, unsigned long long* __restrict__ psum)
{
  int tid = threadIdx.x, lane = tid & 63, wv = tid >> 6;
  __shared__ float sP[4][8];
  __shared__ int   sC[4][8];
  float pacc[8]; int cacc[8];
  #pragma unroll
  for (int e = 0; e < 8; ++e) { pacc[e] = 0.f; cacc[e] = 0; }

  #pragma unroll 1
  for (int it = 0; it < 4; ++it) {
    int t = blockIdx.x * 16 + wv * 4 + it;
    const float4* xr = (const float4*)(x + (size_t)t * DIM);
    float acc[8];
    #pragma unroll
    for (int e = 0; e < 8; ++e) acc[e] = 0.f;
    #pragma unroll 1
    for (int i = 0; i < 8; ++i) {
      int j = i * 64 + lane;
      float4 v = xr[j];
      ushort4 o; o.x = f2bf(v.x); o.y = f2bf(v.y); o.z = f2bf(v.z); o.w = f2bf(v.w);
      *(ushort4*)(xb + (size_t)t * DIM + (size_t)j * 4) = o;
      const float* rr = rw + (size_t)j * 32;
      #pragma unroll
      for (int c = 0; c < 4; ++c) {
        float xv = (&v.x)[c];
        const float4* r4 = (const float4*)(rr + c * 8);
        float4 q0 = r4[0], q1 = r4[1];
        acc[0] += xv * q0.x; acc[1] += xv * q0.y; acc[2] += xv * q0.z; acc[3] += xv * q0.w;
        acc[4] += xv * q1.x; acc[5] += xv * q1.y; acc[6] += xv * q1.z; acc[7] += xv * q1.w;
      }
    }
    #pragma unroll
    for (int off = 32; off; off >>= 1) {
      #pragma unroll
      for (int e = 0; e < 8; ++e) acc[e] += __shfl_xor(acc[e], off);
    }
    float m = acc[0];
    #pragma unroll
    for (int e = 1; e < 8; ++e) m = fmaxf(m, acc[e]);
    float p[8], s = 0.f;
    #pragma unroll
    for (int e = 0; e < 8; ++e) { p[e] = __expf(acc[e] - m); s += p[e]; }
    float inv = 1.f / s;
    int i1 = 0; float p1 = p[0];
    #pragma unroll
    for (int e = 1; e < 8; ++e) if (p[e] > p1) { p1 = p[e]; i1 = e; }
    int i2 = -1; float p2 = -1.f;
    #pragma unroll
    for (int e = 0; e < 8; ++e) if (e != i1 && p[e] > p2) { p2 = p[e]; i2 = e; }
    float w1 = p1 / (p1 + p2);
    if (lane == 0) {
      topi[t] = i1 | (i2 << 8);
      topw[t] = w1;
      #pragma unroll
      for (int e = 0; e < 8; ++e) pacc[e] += p[e] * inv;
      cacc[i1]++; cacc[i2]++;
    }
  }
  if (lane == 0) {
    #pragma unroll
    for (int e = 0; e < 8; ++e) { sP[wv][e] = pacc[e]; sC[wv][e] = cacc[e]; }
  }
  __syncthreads();
  if (tid < 8) {
    float ps = sP[0][tid] + sP[1][tid] + sP[2][tid] + sP[3][tid];
    int   cs = sC[0][tid] + sC[1][tid] + sC[2][tid] + sC[3][tid];
    atomicAdd(&cnt[tid], cs);
    atomicAdd(&psum[tid], (unsigned long long)((double)ps * 1099511627776.0));
  }
}

// ---------------- scan + aux ----------------
__global__ void scan_aux_kernel(int* __restrict__ stats,
                                const unsigned long long* __restrict__ psum,
                                float* __restrict__ aux_out)
{
  if (threadIdx.x == 0 && blockIdx.x == 0) {
    int b = 0;
    for (int e = 0; e < 8; ++e) { stats[16 + e] = b; stats[8 + e] = b; b += stats[e]; }
    double s = 0.0;
    for (int e = 0; e < 8; ++e)
      s += (double)stats[e] * ((double)psum[e] * (1.0 / 1099511627776.0));
    aux_out[0] = (float)(4.0 * s / ((double)N_TOK * (double)N_TOK));
  }
}

// ---------------- placement ----------------
__global__ __launch_bounds__(256) void place_kernel(
    const int* __restrict__ topi, const float* __restrict__ topw,
    int* __restrict__ stats, int* __restrict__ lpk, float* __restrict__ lw)
{
  int t = blockIdx.x * 256 + threadIdx.x;
  if (t >= N_TOK) return;
  int pk = topi[t];
  int e1 = pk & 0xff, e2 = (pk >> 8) & 0xff;
  float w1 = topw[t];
  int p1 = atomicAdd(&stats[8 + e1], 1);
  lpk[p1] = (t << 1); lw[p1] = w1;
  int p2 = atomicAdd(&stats[8 + e2], 1);
  lpk[p2] = (t << 1) | 1; lw[p2] = 1.f - w1;
}

// ---------------- transpose-convert f32 -> bf16 ----------------
__global__ __launch_bounds__(256) void conv_t_kernel(
    const float* __restrict__ src, ushort* __restrict__ dst, int R, int C)
{
  __shared__ float t[32][33];
  int e = blockIdx.z;
  int rb = blockIdx.y << 5, cb = blockIdx.x << 5;
  int x = threadIdx.x & 31, y = threadIdx.x >> 5;
  const float* s = src + ((size_t)e * R + rb) * C + cb;
  #pragma unroll
  for (int i = 0; i < 4; ++i) t[y + i * 8][x] = s[(size_t)(y + i * 8) * C + x];
  __syncthreads();
  ushort* d = dst + ((size_t)e * C + cb) * R + rb;
  #pragma unroll
  for (int i = 0; i < 4; ++i) { int c = y + i * 8; d[(size_t)c * R + x] = f2bf(t[x][c]); }
}

// =====================================================================
// GEMM1: h = silu(x@Wg)*(x@Wu).  BM=128,BN=256,BK=32, 8 waves (2Mx4N),
// 3-buf LDS pipeline, prefetch distance 2, counted vmcnt, swizzled LDS.
// LDS: A 3x8K @0 ; Bg 3x16K @24576 ; Bu 3x16K @73728 ; rofs @122880.
// =====================================================================
__global__ __launch_bounds__(512, 2) void gemm_gateup_kernel(
    const ushort* __restrict__ xb, const ushort* __restrict__ wgt,
    const ushort* __restrict__ wut, const int* __restrict__ lpk,
    const int* __restrict__ stats, ushort* __restrict__ h)
{
  int e = blockIdx.z;
  int Me = stats[e];
  int tm = blockIdx.x;
  if (tm * 128 >= Me) return;
  int abase = stats[16 + e];
  int tn = blockIdx.y;

  extern __shared__ char sm[];
  int* rofs = (int*)(sm + 122880);

  int tid = threadIdx.x, lane = tid & 63, wv = tid >> 6;
  if (tid < 128) {
    int gr = tm * 128 + tid;
    int pk = lpk[abase + ((gr < Me) ? gr : 0)];
    rofs[tid] = (pk >> 1) * DIM;
  }
  __syncthreads();

  // ---- staging source setup (pre-swizzled) ----
  int rA, sA;  decode(tid, rA, sA);              // A unit: 128 rows
  int rB2, sB2; decode(tid + 512, rB2, sB2);     // B units: 256 rows, 2nd half
  const ushort* aS = xb + (size_t)rofs[rA] + sA * 8;
  int g1 = tn * 256 + rA;  if (g1 >= FFN) g1 = FFN - 1;
  int g2 = tn * 256 + rB2; if (g2 >= FFN) g2 = FFN - 1;
  const ushort* gS1 = wgt + ((size_t)e * FFN + g1) * DIM + sA * 8;
  const ushort* gS2 = wgt + ((size_t)e * FFN + g2) * DIM + sB2 * 8;
  const ushort* uS1 = wut + ((size_t)e * FFN + g1) * DIM + sA * 8;
  const ushort* uS2 = wut + ((size_t)e * FFN + g2) * DIM + sB2 * 8;

  // ---- ds_read addresses (within-unit, swizzled) ----
  int wm = wv >> 2, wn = wv & 3;
  int adA[4], adB[4];
  #pragma unroll
  for (int m = 0; m < 4; ++m) adA[m] = swz(wm * 64 + m * 16 + (lane & 15), lane >> 4);
  #pragma unroll
  for (int n = 0; n < 4; ++n) adB[n] = swz(wn * 64 + n * 16 + (lane & 15), lane >> 4);

  f32x4 accg[4][4], accu[4][4];
  #pragma unroll
  for (int m = 0; m < 4; ++m)
    #pragma unroll
    for (int n = 0; n < 4; ++n) { accg[m][n] = (f32x4){0,0,0,0}; accu[m][n] = (f32x4){0,0,0,0}; }

  int wb = wv * 1024;
  // ---- prologue: stage tiles 0,1 into bufs 0,1 (order A,Bg,Bg,Bu,Bu) ----
  #pragma unroll
  for (int t = 0; t < 2; ++t) {
    int k0 = t * 32;
    gload16(aS + k0,  sm + t * 8192 + wb);
    gload16(gS1 + k0, sm + 24576 + t * 16384 + wb);
    gload16(gS2 + k0, sm + 24576 + t * 16384 + 8192 + wb);
    gload16(uS1 + k0, sm + 73728 + t * 16384 + wb);
    gload16(uS2 + k0, sm + 73728 + t * 16384 + 8192 + wb);
  }

  int cur = 0, st = 2;
  #pragma unroll 1
  for (int kt = 0; kt < 64; ++kt) {
    int aB = cur * 8192, gB = 24576 + cur * 16384, uB = 73728 + cur * 16384;
    int aW = st * 8192,  gW = 24576 + st * 16384,  uW = 73728 + st * 16384;
    int kk = kt * 32 + 64;
    bool pf = (kt < 62);
    // ---------- phase 1: gate ----------
    if (pf) {
      gload16(aS + kk,  sm + aW + wb);
      gload16(gS1 + kk, sm + gW + wb);
      gload16(gS2 + kk, sm + gW + 8192 + wb);
    }
    if (kt < 62)       asm volatile("s_waitcnt vmcnt(10)" ::: "memory");
    else if (kt == 62) asm volatile("s_waitcnt vmcnt(7)"  ::: "memory");
    else               asm volatile("s_waitcnt vmcnt(2)"  ::: "memory");
    BAR();
    int4v va[4], vg[4];
    #pragma unroll
    for (int m = 0; m < 4; ++m) va[m] = dsread(aB + adA[m]);
    #pragma unroll
    for (int n = 0; n < 4; ++n) vg[n] = dsread(gB + adB[n]);
    WAITL();
    __builtin_amdgcn_s_setprio(1);
    #pragma unroll
    for (int m = 0; m < 4; ++m)
      #pragma unroll
      for (int n = 0; n < 4; ++n)
        accg[m][n] = MFMA16(BC(va[m]), BC(vg[n]), accg[m][n]);
    __builtin_amdgcn_s_setprio(0);
    // ---------- phase 2: up ----------
    if (pf) {
      gload16(uS1 + kk, sm + uW + wb);
      gload16(uS2 + kk, sm + uW + 8192 + wb);
    }
    if (kt < 62)       asm volatile("s_waitcnt vmcnt(10)" ::: "memory");
    else if (kt == 62) asm volatile("s_waitcnt vmcnt(5)"  ::: "memory");
    else               asm volatile("s_waitcnt vmcnt(0)"  ::: "memory");
    BAR();
    int4v vu[4];
    #pragma unroll
    for (int n = 0; n < 4; ++n) vu[n] = dsread(uB + adB[n]);
    WAITL();
    __builtin_amdgcn_s_setprio(1);
    #pragma unroll
    for (int m = 0; m < 4; ++m)
      #pragma unroll
      for (int n = 0; n < 4; ++n)
        accu[m][n] = MFMA16(BC(va[m]), BC(vu[n]), accu[m][n]);
    __builtin_amdgcn_s_setprio(0);
    BAR();
    cur = (cur == 2) ? 0 : cur + 1;
    st  = (st  == 2) ? 0 : st  + 1;
  }

  // ---- epilogue: fused SiLU ----
  int c = lane & 15, r0 = (lane >> 4) * 4;
  #pragma unroll
  for (int m = 0; m < 4; ++m)
    #pragma unroll
    for (int n = 0; n < 4; ++n)
      #pragma unroll
      for (int r = 0; r < 4; ++r) {
        int row = wm * 64 + m * 16 + r0 + r;
        int col = tn * 256 + wn * 64 + n * 16 + c;
        if (tm * 128 + row < Me && col < FFN) {
          float g = accg[m][n][r], u = accu[m][n][r];
          h[(size_t)(abase + tm * 128 + row) * FFN + col] = f2bf(g * u / (1.f + __expf(-g)));
        }
      }
}

// =====================================================================
// GEMM2: out += w * (h @ WdT).  Same pipeline, single output.
// LDS: A 3x8K @0 ; B 3x16K @24576 ; pkl @73728 ; wl @74240.
// =====================================================================
__global__ __launch_bounds__(512, 2) void gemm_down_kernel(
    const ushort* __restrict__ h, const ushort* __restrict__ wdt,
    const int* __restrict__ lpk, const float* __restrict__ lw,
    const int* __restrict__ stats, float* __restrict__ out)
{
  int e = blockIdx.z;
  int Me = stats[e];
  int tm = blockIdx.x;
  if (tm * 128 >= Me) return;
  int abase = stats[16 + e];
  int tn = blockIdx.y;

  extern __shared__ char sm[];
  int*   pkl = (int*)(sm + 73728);
  float* wl  = (float*)(sm + 74240);

  int tid = threadIdx.x, lane = tid & 63, wv = tid >> 6;
  if (tid < 128) {
    int gr = tm * 128 + tid;
    pkl[tid] = (gr < Me) ? lpk[abase + gr] : 0;
    wl[tid]  = (gr < Me) ? lw[abase + gr] : 0.f;
  }
  __syncthreads();

  int rA, sA;   decode(tid, rA, sA);
  int rB2, sB2; decode(tid + 512, rB2, sB2);
  int arow = abase + tm * 128 + rA; if (arow > N_TOK * 2 - 1) arow = N_TOK * 2 - 1;
  const ushort* aS  = h + (size_t)arow * FFN + sA * 8;
  const ushort* bS1 = wdt + ((size_t)e * DIM + tn * 256 + rA)  * FFN + sA * 8;
  const ushort* bS2 = wdt + ((size_t)e * DIM + tn * 256 + rB2) * FFN + sB2 * 8;

  int wm = wv >> 2, wn = wv & 3;
  int adA[4], adB[4];
  #pragma unroll
  for (int m = 0; m < 4; ++m) adA[m] = swz(wm * 64 + m * 16 + (lane & 15), lane >> 4);
  #pragma unroll
  for (int n = 0; n < 4; ++n) adB[n] = swz(wn * 64 + n * 16 + (lane & 15), lane >> 4);

  f32x4 acc[4][4];
  #pragma unroll
  for (int m = 0; m < 4; ++m)
    #pragma unroll
    for (int n = 0; n < 4; ++n) acc[m][n] = (f32x4){0,0,0,0};

  int wb = wv * 1024;
  #pragma unroll
  for (int t = 0; t < 2; ++t) {
    int k0 = t * 32;
    gload16(aS + k0,  sm + t * 8192 + wb);
    gload16(bS1 + k0, sm + 24576 + t * 16384 + wb);
    gload16(bS2 + k0, sm + 24576 + t * 16384 + 8192 + wb);
  }

  int cur = 0, st = 2;
  #pragma unroll 1
  for (int kt = 0; kt < 44; ++kt) {
    int aB = cur * 8192, bB = 24576 + cur * 16384;
    int aW = st * 8192,  bW = 24576 + st * 16384;
    int kk = kt * 32 + 64;
    bool pf = (kt < 42);
    // ---------- phase 1: n = 0,1 ----------
    if (pf) {
      gload16(aS + kk,  sm + aW + wb);
      gload16(bS1 + kk, sm + bW + wb);
    }
    if (kt < 42)       asm volatile("s_waitcnt vmcnt(5)" ::: "memory");
    else if (kt == 42) asm volatile("s_waitcnt vmcnt(3)" ::: "memory");
    else               asm volatile("s_waitcnt vmcnt(0)" ::: "memory");
    BAR();
    int4v va[4], vb0, vb1;
    #pragma unroll
    for (int m = 0; m < 4; ++m) va[m] = dsread(aB + adA[m]);
    vb0 = dsread(bB + adB[0]);
    vb1 = dsread(bB + adB[1]);
    WAITL();
    __builtin_amdgcn_s_setprio(1);
    #pragma unroll
    for (int m = 0; m < 4; ++m) {
      acc[m][0] = MFMA16(BC(va[m]), BC(vb0), acc[m][0]);
      acc[m][1] = MFMA16(BC(va[m]), BC(vb1), acc[m][1]);
    }
    __builtin_amdgcn_s_setprio(0);
    // ---------- phase 2: n = 2,3 ----------
    if (pf) gload16(bS2 + kk, sm + bW + 8192 + wb);
    int4v vb2 = dsread(bB + adB[2]);
    int4v vb3 = dsread(bB + adB[3]);
    WAITL();
    __builtin_amdgcn_s_setprio(1);
    #pragma unroll
    for (int m = 0; m < 4; ++m) {
      acc[m][2] = MFMA16(BC(va[m]), BC(vb2), acc[m][2]);
      acc[m][3] = MFMA16(BC(va[m]), BC(vb3), acc[m][3]);
    }
    __builtin_amdgcn_s_setprio(0);
    BAR();
    cur = (cur == 2) ? 0 : cur + 1;
    st  = (st  == 2) ? 0 : st  + 1;
  }

  int c = lane & 15, r0 = (lane >> 4) * 4;
  #pragma unroll
  for (int m = 0; m < 4; ++m)
    #pragma unroll
    for (int n = 0; n < 4; ++n)
      #pragma unroll
      for (int r = 0; r < 4; ++r) {
        int row = wm * 64 + m * 16 + r0 + r;
        if (tm * 128 + row < Me) {
          int t = pkl[row] >> 1;
          float val = wl[row] * acc[m][n][r];
          unsafeAtomicAdd(&out[(size_t)t * DIM + tn * 256 + wn * 64 + n * 16 + c], val);
        }
      }
}

extern "C" void kernel_launch(void* const* d_in, const int* in_sizes, int n_in,
                              void* d_out, int out_size, void* d_ws, size_t ws_size,
                              hipStream_t stream)
{
  const float* x  = (const float*)d_in[0];
  const float* rw = (const float*)d_in[1];
  const float* wg = (const float*)d_in[2];
  const float* wu = (const float*)d_in[3];
  const float* wd = (const float*)d_in[4];
  float* out = (float*)d_out;

  char* ws = (char*)d_ws;
  ushort* xb   = (ushort*)(ws + X_OFF);
  ushort* wgt  = (ushort*)(ws + WG_OFF);
  ushort* wut  = (ushort*)(ws + WU_OFF);
  ushort* wdt  = (ushort*)(ws + WD_OFF);
  ushort* hbuf = (ushort*)(ws + H_OFF);
  int*    lpk  = (int*)(ws + LPK_OFF);
  float*  lw   = (float*)(ws + LW_OFF);
  int*    topi = (int*)(ws + TI_OFF);
  float*  topw = (float*)(ws + TW_OFF);
  int*    stats = (int*)(ws + ST_OFF);
  unsigned long long* psum = (unsigned long long*)(ws + ST_OFF + 96);

  hipMemsetAsync(d_out, 0, (size_t)out_size * sizeof(float), stream);
  hipMemsetAsync(ws + ST_OFF, 0, 160, stream);

  router_kernel<<<512, 256, 0, stream>>>(x, rw, xb, topi, topw, stats, psum);
  scan_aux_kernel<<<1, 64, 0, stream>>>(stats, psum, out + (size_t)out_size - 1);
  place_kernel<<<32, 256, 0, stream>>>(topi, topw, stats, lpk, lw);

  conv_t_kernel<<<dim3(44, 64, 8), 256, 0, stream>>>(wg, wgt, DIM, FFN);
  conv_t_kernel<<<dim3(44, 64, 8), 256, 0, stream>>>(wu, wut, DIM, FFN);
  conv_t_kernel<<<dim3(64, 44, 8), 256, 0, stream>>>(wd, wdt, FFN, DIM);

  gemm_gateup_kernel<<<dim3(128, 6, 8), 512, 123392, stream>>>(xb, wgt, wut, lpk, stats, hbuf);
  gemm_down_kernel<<<dim3(128, 8, 8), 512, 74752, stream>>>(hbuf, wdt, lpk, lw, stats, out);
}